// Round 3
// baseline (54.052 us; speedup 1.0000x reference)
//
#include <hip/hip_runtime.h>

// hidden_layers: (4, B, T, D) float32
// word_ids:      (B, T) int32, SORTED along T, values in [0, W] (W = NONE)
// output:        (B*(W+1), D) float32; row (b,0)=CLS = mean-over-layers of
//                token 0; row (b,1+w)=segment mean of layer-mean over tokens
//                with word_ids[b,t]==w (0 if empty segment).
#define NB 32
#define NT 512
#define ND 1024
#define NW 100
#define NL 4

// One wave per output row. Segment boundaries found with a wave-cooperative
// ballot scan (8 parallel coalesced loads, no dependent-load chain), token
// loop unrolled x2 (32 independent float4 loads in flight per wave).
__global__ __launch_bounds__(64) void bert_word_pool_kernel(
    const float* __restrict__ hidden,   // (NL, NB, NT, ND)
    const int*   __restrict__ word_ids, // (NB, NT)
    float*       __restrict__ out)      // (NB*(NW+1), ND)
{
    const int row  = blockIdx.x;          // 0 .. NB*(NW+1)-1
    const int b    = row / (NW + 1);
    const int j    = row - b * (NW + 1);  // 0 = cls, 1..NW = word (j-1)
    const int lane = threadIdx.x;         // 0..63

    const size_t layer_stride = (size_t)NB * NT * ND;
    const float* hb = hidden + (size_t)b * NT * ND;

    int start, count;
    if (j == 0) {
        start = 0; count = 1;             // CLS: token 0 only
    } else {
        const int w = j - 1;
        const int* ids = word_ids + b * NT;
        // Wave-cooperative search: lane L holds ids[k*64 + L], k=0..7.
        int idv[8];
        #pragma unroll
        for (int k = 0; k < 8; ++k) idv[k] = ids[k * 64 + lane];

        int sv = NT, ev = NT;
        #pragma unroll
        for (int k = 7; k >= 0; --k) {     // lowest k wins (overwrites)
            unsigned long long m = __ballot(idv[k] >= w);
            if (m) sv = k * 64 + (int)__builtin_ctzll(m);
        }
        #pragma unroll
        for (int k = 7; k >= 0; --k) {
            unsigned long long m = __ballot(idv[k] > w);
            if (m) ev = k * 64 + (int)__builtin_ctzll(m);
        }
        start = sv; count = ev - sv;
    }
    const int end = start + count;

    float4 acc[4];
    #pragma unroll
    for (int c = 0; c < 4; ++c) acc[c] = make_float4(0.f, 0.f, 0.f, 0.f);

    int t = start;
    // Unrolled x2: 32 independent float4 loads issued before accumulation.
    for (; t + 2 <= end; t += 2) {
        const float* p0 = hb + (size_t)t * ND + lane * 4;
        const float* p1 = p0 + ND;
        float4 u[NL][4], v[NL][4];
        #pragma unroll
        for (int l = 0; l < NL; ++l) {
            #pragma unroll
            for (int c = 0; c < 4; ++c) {
                u[l][c] = *reinterpret_cast<const float4*>(p0 + (size_t)l * layer_stride + c * 256);
                v[l][c] = *reinterpret_cast<const float4*>(p1 + (size_t)l * layer_stride + c * 256);
            }
        }
        #pragma unroll
        for (int l = 0; l < NL; ++l) {
            #pragma unroll
            for (int c = 0; c < 4; ++c) {
                acc[c].x += u[l][c].x + v[l][c].x;
                acc[c].y += u[l][c].y + v[l][c].y;
                acc[c].z += u[l][c].z + v[l][c].z;
                acc[c].w += u[l][c].w + v[l][c].w;
            }
        }
    }
    if (t < end) {
        const float* p0 = hb + (size_t)t * ND + lane * 4;
        float4 u[NL][4];
        #pragma unroll
        for (int l = 0; l < NL; ++l)
            #pragma unroll
            for (int c = 0; c < 4; ++c)
                u[l][c] = *reinterpret_cast<const float4*>(p0 + (size_t)l * layer_stride + c * 256);
        #pragma unroll
        for (int l = 0; l < NL; ++l) {
            #pragma unroll
            for (int c = 0; c < 4; ++c) {
                acc[c].x += u[l][c].x; acc[c].y += u[l][c].y;
                acc[c].z += u[l][c].z; acc[c].w += u[l][c].w;
            }
        }
    }

    const float scale = (count > 0) ? (1.0f / (float)(NL * count)) : 0.0f;
    float* op = out + (size_t)row * ND + lane * 4;
    #pragma unroll
    for (int c = 0; c < 4; ++c) {
        float4 r = make_float4(acc[c].x * scale, acc[c].y * scale,
                               acc[c].z * scale, acc[c].w * scale);
        *reinterpret_cast<float4*>(op + c * 256) = r;
    }
}

extern "C" void kernel_launch(void* const* d_in, const int* in_sizes, int n_in,
                              void* d_out, int out_size, void* d_ws, size_t ws_size,
                              hipStream_t stream) {
    const float* hidden   = (const float*)d_in[0];
    const int*   word_ids = (const int*)d_in[1];
    // d_in[2] = num_words scalar (==100), compiled in as NW.
    float* out = (float*)d_out;

    const int rows = NB * (NW + 1);   // 3232 blocks, 1 wave each
    bert_word_pool_kernel<<<rows, 64, 0, stream>>>(hidden, word_ids, out);
}

// Round 4
// 47.229 us; speedup vs baseline: 1.1445x; 1.1445x over previous
//
#include <hip/hip_runtime.h>

// hidden_layers: (4, B, T, D) float32
// word_ids:      (B, T) int32, SORTED along T, values in [0, W] (W = NONE)
// output:        (B*(W+1), D) float32; row (b,0)=CLS = mean-over-layers of
//                token 0; row (b,1+w)=segment mean of layer-mean over tokens
//                with word_ids[b,t]==w (0 if empty segment).
#define NB 32
#define NT 512
#define ND 1024
#define NW 100
#define NL 4
#define NQ 4            // D split into quarters -> 4x finer work granules
#define QD (ND / NQ)    // 256 floats = 1 KB per quarter

// One wave per (output row, D-quarter). Work granule = count*4layers*1KB
// (~20 KB) instead of ~80 KB -> dynamic block refill smooths the CU tail.
// Each token-layer-quarter read is exactly one coalesced 64-lane float4 load.
__global__ __launch_bounds__(64) void bert_word_pool_kernel(
    const float* __restrict__ hidden,   // (NL, NB, NT, ND)
    const int*   __restrict__ word_ids, // (NB, NT)
    float*       __restrict__ out)      // (NB*(NW+1), ND)
{
    const int bid  = blockIdx.x;         // row * NQ + q
    const int row  = bid >> 2;
    const int q    = bid & (NQ - 1);
    const int b    = row / (NW + 1);
    const int j    = row - b * (NW + 1); // 0 = cls, 1..NW = word (j-1)
    const int lane = threadIdx.x;        // 0..63

    const size_t layer_stride = (size_t)NB * NT * ND;

    int start, count;
    if (j == 0) {
        start = 0; count = 1;            // CLS: token 0 only
    } else {
        const int w = j - 1;
        const int* ids = word_ids + b * NT;
        // Wave-cooperative search: lane L holds ids[k*64 + L], k=0..7.
        int idv[8];
        #pragma unroll
        for (int k = 0; k < 8; ++k) idv[k] = ids[k * 64 + lane];

        int sv = NT, ev = NT;
        #pragma unroll
        for (int k = 7; k >= 0; --k) {    // lowest k wins (overwrites)
            unsigned long long m = __ballot(idv[k] >= w);
            if (m) sv = k * 64 + (int)__builtin_ctzll(m);
        }
        #pragma unroll
        for (int k = 7; k >= 0; --k) {
            unsigned long long m = __ballot(idv[k] > w);
            if (m) ev = k * 64 + (int)__builtin_ctzll(m);
        }
        start = sv; count = ev - sv;
    }
    const int end = start + count;

    // Base pointer for this (batch, quarter, lane).
    const float* hp = hidden + (size_t)b * NT * ND + q * QD + lane * 4;

    float4 acc = make_float4(0.f, 0.f, 0.f, 0.f);

    int t = start;
    for (; t + 2 <= end; t += 2) {       // x2 unroll: 8 loads in flight
        const float* p0 = hp + (size_t)t * ND;
        const float* p1 = p0 + ND;
        float4 u[NL], v[NL];
        #pragma unroll
        for (int l = 0; l < NL; ++l) {
            u[l] = *reinterpret_cast<const float4*>(p0 + (size_t)l * layer_stride);
            v[l] = *reinterpret_cast<const float4*>(p1 + (size_t)l * layer_stride);
        }
        #pragma unroll
        for (int l = 0; l < NL; ++l) {
            acc.x += u[l].x + v[l].x;
            acc.y += u[l].y + v[l].y;
            acc.z += u[l].z + v[l].z;
            acc.w += u[l].w + v[l].w;
        }
    }
    if (t < end) {
        const float* p0 = hp + (size_t)t * ND;
        float4 u[NL];
        #pragma unroll
        for (int l = 0; l < NL; ++l)
            u[l] = *reinterpret_cast<const float4*>(p0 + (size_t)l * layer_stride);
        #pragma unroll
        for (int l = 0; l < NL; ++l) {
            acc.x += u[l].x; acc.y += u[l].y;
            acc.z += u[l].z; acc.w += u[l].w;
        }
    }

    const float scale = (count > 0) ? (1.0f / (float)(NL * count)) : 0.0f;
    float4 r = make_float4(acc.x * scale, acc.y * scale,
                           acc.z * scale, acc.w * scale);
    *reinterpret_cast<float4*>(out + (size_t)row * ND + q * QD + lane * 4) = r;
}

extern "C" void kernel_launch(void* const* d_in, const int* in_sizes, int n_in,
                              void* d_out, int out_size, void* d_ws, size_t ws_size,
                              hipStream_t stream) {
    const float* hidden   = (const float*)d_in[0];
    const int*   word_ids = (const int*)d_in[1];
    // d_in[2] = num_words scalar (==100), compiled in as NW.
    float* out = (float*)d_out;

    const int blocks = NB * (NW + 1) * NQ;   // 12928 blocks, 1 wave each
    bert_word_pool_kernel<<<blocks, 64, 0, stream>>>(hidden, word_ids, out);
}

// Round 5
// 45.944 us; speedup vs baseline: 1.1765x; 1.0280x over previous
//
#include <hip/hip_runtime.h>

// hidden_layers: (4, B, T, D) float32
// word_ids:      (B, T) int32, SORTED along T, values in [0, W] (W = NONE)
// output:        (B*(W+1), D) float32; row (b,0)=CLS = mean-over-layers of
//                token 0; row (b,1+w)=segment mean of layer-mean over tokens
//                with word_ids[b,t]==w (0 if empty segment).
#define NB 32
#define NT 512
#define ND 1024
#define NW 100
#define NL 4
#define NQ 8            // D split into eighths -> ~10 KB work granules
#define QD (ND / NQ)    // 128 floats = 512 B per slice

// One wave per (output row, D-eighth). Each lane owns 2 floats (float2,
// 8 B/lane -> still fully coalesced 512 B wave-loads). Granule halved vs
// NQ=4 to shrink the CU straggler tail (the confirmed limiter, R3->R4).
__global__ __launch_bounds__(64) void bert_word_pool_kernel(
    const float* __restrict__ hidden,   // (NL, NB, NT, ND)
    const int*   __restrict__ word_ids, // (NB, NT)
    float*       __restrict__ out)      // (NB*(NW+1), ND)
{
    const int bid  = blockIdx.x;         // row * NQ + q
    const int row  = bid >> 3;
    const int q    = bid & (NQ - 1);
    const int b    = row / (NW + 1);
    const int j    = row - b * (NW + 1); // 0 = cls, 1..NW = word (j-1)
    const int lane = threadIdx.x;        // 0..63

    const size_t layer_stride = (size_t)NB * NT * ND;

    int start, count;
    if (j == 0) {
        start = 0; count = 1;            // CLS: token 0 only
    } else {
        const int w = j - 1;
        const int* ids = word_ids + b * NT;
        // Wave-cooperative search: lane L holds ids[k*64 + L], k=0..7.
        int idv[8];
        #pragma unroll
        for (int k = 0; k < 8; ++k) idv[k] = ids[k * 64 + lane];

        int sv = NT, ev = NT;
        #pragma unroll
        for (int k = 7; k >= 0; --k) {    // lowest k wins (overwrites)
            unsigned long long m = __ballot(idv[k] >= w);
            if (m) sv = k * 64 + (int)__builtin_ctzll(m);
        }
        #pragma unroll
        for (int k = 7; k >= 0; --k) {
            unsigned long long m = __ballot(idv[k] > w);
            if (m) ev = k * 64 + (int)__builtin_ctzll(m);
        }
        start = sv; count = ev - sv;
    }
    const int end = start + count;

    // Base pointer for this (batch, slice, lane).
    const float* hp = hidden + (size_t)b * NT * ND + q * QD + lane * 2;

    float2 acc = make_float2(0.f, 0.f);

    int t = start;
    for (; t + 2 <= end; t += 2) {       // x2 unroll: 8 loads in flight
        const float* p0 = hp + (size_t)t * ND;
        const float* p1 = p0 + ND;
        float2 u[NL], v[NL];
        #pragma unroll
        for (int l = 0; l < NL; ++l) {
            u[l] = *reinterpret_cast<const float2*>(p0 + (size_t)l * layer_stride);
            v[l] = *reinterpret_cast<const float2*>(p1 + (size_t)l * layer_stride);
        }
        #pragma unroll
        for (int l = 0; l < NL; ++l) {
            acc.x += u[l].x + v[l].x;
            acc.y += u[l].y + v[l].y;
        }
    }
    if (t < end) {
        const float* p0 = hp + (size_t)t * ND;
        float2 u[NL];
        #pragma unroll
        for (int l = 0; l < NL; ++l)
            u[l] = *reinterpret_cast<const float2*>(p0 + (size_t)l * layer_stride);
        #pragma unroll
        for (int l = 0; l < NL; ++l) {
            acc.x += u[l].x; acc.y += u[l].y;
        }
    }

    const float scale = (count > 0) ? (1.0f / (float)(NL * count)) : 0.0f;
    float2 r = make_float2(acc.x * scale, acc.y * scale);
    *reinterpret_cast<float2*>(out + (size_t)row * ND + q * QD + lane * 2) = r;
}

extern "C" void kernel_launch(void* const* d_in, const int* in_sizes, int n_in,
                              void* d_out, int out_size, void* d_ws, size_t ws_size,
                              hipStream_t stream) {
    const float* hidden   = (const float*)d_in[0];
    const int*   word_ids = (const int*)d_in[1];
    // d_in[2] = num_words scalar (==100), compiled in as NW.
    float* out = (float*)d_out;

    const int blocks = NB * (NW + 1) * NQ;   // 25856 blocks, 1 wave each
    bert_word_pool_kernel<<<blocks, 64, 0, stream>>>(hidden, word_ids, out);
}